// Round 3
// baseline (504.111 us; speedup 1.0000x reference)
//
#include <hip/hip_runtime.h>
#include <hip/hip_cooperative_groups.h>
#include <float.h>

namespace cg = cooperative_groups;

#define PROMPT_LEN 2048
#define VOCAB 49408
#define DIM 768
#define ROWS_TOTAL (VOCAB + PROMPT_LEN)   // 51456
#define NS 8           // candidate stripes
#define NMI 32         // m-tiles (32*8 == 256 == grid)
#define BM 64          // prompts per tile
#define BN 64          // candidates per tile
#define KCH 128        // k-chunk (bf16 elems)
#define NCHUNK (DIM / KCH)   // 6
#define LDK (KCH + 8)  // LDS pitch in ushorts: 272B -> 2-way bank alias (free)
#define CAND_MAX 4096
#define EPS 0.008f     // fp32 ambiguity margin (validated earlier rounds)

typedef __attribute__((ext_vector_type(8))) short s8v;   // 8 bf16 = 4 VGPR (MFMA A/B frag)
typedef __attribute__((ext_vector_type(4))) float fx4;   // MFMA C/D frag

// ws: csq | cand | candCsq | scal | AB1 | AB2 | AIdx | amb | PbH | PbL | CbH | CbL
// scal: [0]=cand count, [1]=cmin bits, [2]=pmax bits, [3]=amb count
// ws poison 0xAAAAAAAA: atomicMin-on-uint / atomicMax-on-int are poison-safe;
// scal[0], scal[3] zeroed in phase 1 (ordered by grid.sync before first use).

__device__ inline unsigned short f2bf(float x) {         // RN-even f32->bf16
    unsigned u = __float_as_uint(x);
    u += 0x7FFFu + ((u >> 16) & 1u);
    return (unsigned short)(u >> 16);
}

__device__ inline void split_store(float4 x, unsigned short* dH, unsigned short* dL, int idx) {
    ushort4 h, l;
    h.x = f2bf(x.x); l.x = f2bf(x.x - __uint_as_float((unsigned)h.x << 16));
    h.y = f2bf(x.y); l.y = f2bf(x.y - __uint_as_float((unsigned)h.y << 16));
    h.z = f2bf(x.z); l.z = f2bf(x.z - __uint_as_float((unsigned)h.z << 16));
    h.w = f2bf(x.w); l.w = f2bf(x.w - __uint_as_float((unsigned)h.w << 16));
    ((ushort4*)dH)[idx] = h;
    ((ushort4*)dL)[idx] = l;
}

__device__ inline void conv_row(const float* __restrict__ src,
                                unsigned short* __restrict__ dH,
                                unsigned short* __restrict__ dL, int lane) {
    #pragma unroll
    for (int i = 0; i < 3; ++i) {
        float4 x = ((const float4*)src)[i * 64 + lane];
        split_store(x, dH, dL, i * 64 + lane);
    }
}

__device__ inline void merge2(float& b1, float& b2, int& bi,
                              float y1, float y2, int yi) {
    if (y1 < b1) { b2 = fminf(b1, y2); b1 = y1; bi = yi; }
    else         { b2 = fminf(b2, fminf(y1, y2)); }
}

// ---------------- the whole pipeline as one cooperative kernel ----------------
// grid 256 x 256 threads: exactly 1 block/CU (co-residency trivially satisfied).
__global__ void __launch_bounds__(256)
k_all(const float* __restrict__ prompt, const float* __restrict__ clip,
      float* __restrict__ csq, int* __restrict__ cand, float* __restrict__ candCsq,
      unsigned* __restrict__ scal,
      float* __restrict__ AB1, float* __restrict__ AB2, int* __restrict__ AIdx,
      int* __restrict__ amb,
      unsigned short* __restrict__ PbH, unsigned short* __restrict__ PbL,
      unsigned short* __restrict__ CbH, unsigned short* __restrict__ CbL,
      float* __restrict__ out) {
    cg::grid_group grid = cg::this_grid();

    int tid  = threadIdx.x;
    int wid  = tid >> 6;
    int lane = tid & 63;
    int bx   = blockIdx.x;

    __shared__ unsigned short Ah[BM][LDK], Al[BM][LDK];
    __shared__ unsigned short Bh[BN][LDK], Bl[BN][LDK];
    __shared__ int   candS[BN];
    __shared__ float csqS[BN];
    __shared__ float mB1[BM][2], mB2[BM][2];
    __shared__ int   mBI[BM][2];
    __shared__ int   kvS[256];
    __shared__ int   cntS, basep;
    __shared__ float smn[4], smx[4];
    __shared__ double fB[4];
    __shared__ int    fI[4], sWin;

    // ======== phase 1: sumsq (+ prompt split-bf16 conversion, minmax) ========
    if (bx == 0 && tid == 0) { scal[0] = 0u; scal[3] = 0u; }
    {
        int gw = bx * 4 + wid;            // 0..1023
        float locMin = FLT_MAX, locMax = 0.f;
        for (int r0 = gw; r0 < ROWS_TOTAL; r0 += 2048) {
            int r1 = r0 + 1024;
            int v1 = (r1 < ROWS_TOTAL);
            const float* s0 = (r0 < VOCAB) ? clip + (size_t)r0 * DIM
                                           : prompt + (size_t)(r0 - VOCAB) * DIM;
            const float* s1 = v1 ? ((r1 < VOCAB) ? clip + (size_t)r1 * DIM
                                                 : prompt + (size_t)(r1 - VOCAB) * DIM)
                                 : s0;
            float4 a0 = ((const float4*)s0)[lane];
            float4 a1 = ((const float4*)s0)[64 + lane];
            float4 a2 = ((const float4*)s0)[128 + lane];
            float4 b0 = ((const float4*)s1)[lane];
            float4 b1 = ((const float4*)s1)[64 + lane];
            float4 b2 = ((const float4*)s1)[128 + lane];
            float sA = a0.x*a0.x + a0.y*a0.y + a0.z*a0.z + a0.w*a0.w
                     + a1.x*a1.x + a1.y*a1.y + a1.z*a1.z + a1.w*a1.w
                     + a2.x*a2.x + a2.y*a2.y + a2.z*a2.z + a2.w*a2.w;
            float sB = b0.x*b0.x + b0.y*b0.y + b0.z*b0.z + b0.w*b0.w
                     + b1.x*b1.x + b1.y*b1.y + b1.z*b1.z + b1.w*b1.w
                     + b2.x*b2.x + b2.y*b2.y + b2.z*b2.z + b2.w*b2.w;
            #pragma unroll
            for (int m = 32; m >= 1; m >>= 1) {
                sA += __shfl_xor(sA, m, 64);
                sB += __shfl_xor(sB, m, 64);
            }
            if (r0 < VOCAB) {
                if (lane == 0) csq[r0] = sA;
                locMin = fminf(locMin, sA);
            } else {
                locMax = fmaxf(locMax, sA);
                int pr = r0 - VOCAB;
                unsigned short* dH = PbH + (size_t)pr * DIM;
                unsigned short* dL = PbL + (size_t)pr * DIM;
                split_store(a0, dH, dL, lane);
                split_store(a1, dH, dL, 64 + lane);
                split_store(a2, dH, dL, 128 + lane);
            }
            if (v1) {
                if (r1 < VOCAB) {
                    if (lane == 0) csq[r1] = sB;
                    locMin = fminf(locMin, sB);
                } else {
                    locMax = fmaxf(locMax, sB);
                    int pr = r1 - VOCAB;
                    unsigned short* dH = PbH + (size_t)pr * DIM;
                    unsigned short* dL = PbL + (size_t)pr * DIM;
                    split_store(b0, dH, dL, lane);
                    split_store(b1, dH, dL, 64 + lane);
                    split_store(b2, dH, dL, 128 + lane);
                }
            }
        }
        if (lane == 0) { smn[wid] = locMin; smx[wid] = locMax; }
        __syncthreads();
        if (tid == 0) {
            float mn = FLT_MAX, mx = 0.f;
            #pragma unroll
            for (int w = 0; w < 4; ++w) { mn = fminf(mn, smn[w]); mx = fmaxf(mx, smx[w]); }
            atomicMin(&scal[1], __float_as_uint(mn));          // uint: poison-safe
            atomicMax((int*)&scal[2], (int)__float_as_uint(mx)); // int: poison-safe
        }
    }
    grid.sync();

    // ======== phase 2: compact + candidate split-bf16 conversion ========
    {
        float cmin    = __uint_as_float(scal[1]);
        float pmax_sq = __uint_as_float(scal[2]);
        float B  = sqrtf(pmax_sq) * 1.0001f + 1e-6f;
        float U  = cmin + 2.f * B * sqrtf(cmin) + 1.0f;
        float sT = B + sqrtf(B * B + U);
        float T  = sT * sT;

        int v = bx * 256 + tid;           // 65536 threads cover VOCAB
        if (tid == 0) cntS = 0;
        __syncthreads();
        int keep = (v < VOCAB) && (csq[v] <= T);
        int pos = 0;
        if (keep) pos = atomicAdd(&cntS, 1);
        __syncthreads();
        if (tid == 0 && cntS > 0) basep = atomicAdd((int*)&scal[0], cntS);
        __syncthreads();
        if (keep) {
            int dst = basep + pos;
            cand[dst]    = v;
            candCsq[dst] = csq[v];
            kvS[pos] = v;
        }
        __syncthreads();
        int nk = cntS;
        for (int i = wid; i < nk; i += 4) {
            int dst = basep + i;
            if (dst >= CAND_MAX) break;       // overflow -> all-amb fallback path
            conv_row(clip + (size_t)kvS[i] * DIM,
                     CbH + (size_t)dst * DIM, CbL + (size_t)dst * DIM, lane);
        }
    }
    grid.sync();

    int rawCount = (int)scal[0];
    int count = rawCount > CAND_MAX ? CAND_MAX : rawCount;

    // ======== phase 3: split-bf16 MFMA scorer (NS=8 stripes) ========
    {
        int mi = bx & (NMI - 1);
        int s  = bx >> 5;                 // 0..7
        int m0 = mi * BM;
        int ntiles = (count + BN - 1) / BN;

        int wr32 = (wid >> 1) * 32;
        int wc32 = (wid & 1) * 32;
        int l15  = lane & 15;
        int l4   = lane >> 4;

        int srow[4], scol[4], offA[4];
        #pragma unroll
        for (int f = 0; f < 4; ++f) {
            int j = tid + 256 * f;
            srow[f] = j >> 4;
            scol[f] = (j & 15) * 8;
            offA[f] = (m0 + srow[f]) * DIM + scol[f];
        }

        float rb1[2][4], rb2[2][4]; int rbi[2][4];
        #pragma unroll
        for (int fm = 0; fm < 2; ++fm)
            #pragma unroll
            for (int j = 0; j < 4; ++j) { rb1[fm][j] = FLT_MAX; rb2[fm][j] = FLT_MAX; rbi[fm][j] = 0x7fffffff; }

        for (int tile = s; tile < ntiles; tile += NS) {
            __syncthreads();
            if (tid < BN) {
                int ci = tile * BN + tid;
                candS[tid] = (ci < count) ? cand[ci] : 0;
                csqS[tid]  = (ci < count) ? candCsq[ci] : FLT_MAX;
            }

            int offB[4];
            #pragma unroll
            for (int f = 0; f < 4; ++f) {
                int rowc = tile * BN + srow[f];
                if (rowc >= count) rowc = 0;   // masked via csqS
                offB[f] = rowc * DIM + scol[f];
            }

            fx4 acc00 = {0.f,0.f,0.f,0.f}, acc01 = {0.f,0.f,0.f,0.f};
            fx4 acc10 = {0.f,0.f,0.f,0.f}, acc11 = {0.f,0.f,0.f,0.f};

            s8v rAh[4], rAl[4], rBh[4], rBl[4];
            #pragma unroll
            for (int f = 0; f < 4; ++f) {
                rAh[f] = *(const s8v*)(PbH + offA[f]);
                rAl[f] = *(const s8v*)(PbL + offA[f]);
                rBh[f] = *(const s8v*)(CbH + offB[f]);
                rBl[f] = *(const s8v*)(CbL + offB[f]);
            }

            #pragma unroll
            for (int kc = 0; kc < NCHUNK; ++kc) {
                __syncthreads();
                #pragma unroll
                for (int f = 0; f < 4; ++f) {
                    *(s8v*)&Ah[srow[f]][scol[f]] = rAh[f];
                    *(s8v*)&Al[srow[f]][scol[f]] = rAl[f];
                    *(s8v*)&Bh[srow[f]][scol[f]] = rBh[f];
                    *(s8v*)&Bl[srow[f]][scol[f]] = rBl[f];
                }
                __syncthreads();
                if (kc + 1 < NCHUNK) {
                    int off = (kc + 1) * KCH;
                    #pragma unroll
                    for (int f = 0; f < 4; ++f) {
                        rAh[f] = *(const s8v*)(PbH + offA[f] + off);
                        rAl[f] = *(const s8v*)(PbL + offA[f] + off);
                        rBh[f] = *(const s8v*)(CbH + offB[f] + off);
                        rBl[f] = *(const s8v*)(CbL + offB[f] + off);
                    }
                }
                #pragma unroll
                for (int kk = 0; kk < KCH / 32; ++kk) {
                    int ko = kk * 32 + l4 * 8;
                    s8v ah0 = *(const s8v*)&Ah[wr32      + l15][ko];
                    s8v ah1 = *(const s8v*)&Ah[wr32 + 16 + l15][ko];
                    s8v al0 = *(const s8v*)&Al[wr32      + l15][ko];
                    s8v al1 = *(const s8v*)&Al[wr32 + 16 + l15][ko];
                    s8v bh0 = *(const s8v*)&Bh[wc32      + l15][ko];
                    s8v bh1 = *(const s8v*)&Bh[wc32 + 16 + l15][ko];
                    s8v bl0 = *(const s8v*)&Bl[wc32      + l15][ko];
                    s8v bl1 = *(const s8v*)&Bl[wc32 + 16 + l15][ko];
                    acc00 = __builtin_amdgcn_mfma_f32_16x16x32_bf16(ah0, bh0, acc00, 0, 0, 0);
                    acc01 = __builtin_amdgcn_mfma_f32_16x16x32_bf16(ah0, bh1, acc01, 0, 0, 0);
                    acc10 = __builtin_amdgcn_mfma_f32_16x16x32_bf16(ah1, bh0, acc10, 0, 0, 0);
                    acc11 = __builtin_amdgcn_mfma_f32_16x16x32_bf16(ah1, bh1, acc11, 0, 0, 0);
                    acc00 = __builtin_amdgcn_mfma_f32_16x16x32_bf16(al0, bh0, acc00, 0, 0, 0);
                    acc01 = __builtin_amdgcn_mfma_f32_16x16x32_bf16(al0, bh1, acc01, 0, 0, 0);
                    acc10 = __builtin_amdgcn_mfma_f32_16x16x32_bf16(al1, bh0, acc10, 0, 0, 0);
                    acc11 = __builtin_amdgcn_mfma_f32_16x16x32_bf16(al1, bh1, acc11, 0, 0, 0);
                    acc00 = __builtin_amdgcn_mfma_f32_16x16x32_bf16(ah0, bl0, acc00, 0, 0, 0);
                    acc01 = __builtin_amdgcn_mfma_f32_16x16x32_bf16(ah0, bl1, acc01, 0, 0, 0);
                    acc10 = __builtin_amdgcn_mfma_f32_16x16x32_bf16(ah1, bl0, acc10, 0, 0, 0);
                    acc11 = __builtin_amdgcn_mfma_f32_16x16x32_bf16(ah1, bl1, acc11, 0, 0, 0);
                }
            }

            // fold tile d2. D layout (m89): col = lane&15, row = (lane>>4)*4 + reg.
            float cs0 = csqS[wc32 + l15];       int v0 = candS[wc32 + l15];
            float cs1 = csqS[wc32 + 16 + l15];  int v1 = candS[wc32 + 16 + l15];
            #pragma unroll
            for (int j = 0; j < 4; ++j) {
                if (cs0 < FLT_MAX) {
                    float d2 = fmaf(-2.f, acc00[j], cs0);
                    if (d2 < rb1[0][j]) { rb2[0][j] = rb1[0][j]; rb1[0][j] = d2; rbi[0][j] = v0; }
                    else if (d2 <= rb2[0][j]) rb2[0][j] = d2;
                    d2 = fmaf(-2.f, acc10[j], cs0);
                    if (d2 < rb1[1][j]) { rb2[1][j] = rb1[1][j]; rb1[1][j] = d2; rbi[1][j] = v0; }
                    else if (d2 <= rb2[1][j]) rb2[1][j] = d2;
                }
                if (cs1 < FLT_MAX) {
                    float d2 = fmaf(-2.f, acc01[j], cs1);
                    if (d2 < rb1[0][j]) { rb2[0][j] = rb1[0][j]; rb1[0][j] = d2; rbi[0][j] = v1; }
                    else if (d2 <= rb2[0][j]) rb2[0][j] = d2;
                    d2 = fmaf(-2.f, acc11[j], cs1);
                    if (d2 < rb1[1][j]) { rb2[1][j] = rb1[1][j]; rb1[1][j] = d2; rbi[1][j] = v1; }
                    else if (d2 <= rb2[1][j]) rb2[1][j] = d2;
                }
            }
        }

        __syncthreads();   // protect csqS/candS (loop) vs mB reuse below
        #pragma unroll
        for (int fm = 0; fm < 2; ++fm)
            #pragma unroll
            for (int j = 0; j < 4; ++j) {
                float b1 = rb1[fm][j], b2 = rb2[fm][j]; int bi = rbi[fm][j];
                #pragma unroll
                for (int msk = 1; msk <= 8; msk <<= 1) {
                    float y1 = __shfl_xor(b1, msk, 64);
                    float y2 = __shfl_xor(b2, msk, 64);
                    int   yi = __shfl_xor(bi, msk, 64);
                    merge2(b1, b2, bi, y1, y2, yi);
                }
                if (l15 == 0) {
                    int rl = wr32 + fm * 16 + l4 * 4 + j;
                    mB1[rl][wid & 1] = b1; mB2[rl][wid & 1] = b2; mBI[rl][wid & 1] = bi;
                }
            }
        __syncthreads();
        if (tid < BM) {
            float B1 = mB1[tid][0], B2 = mB2[tid][0]; int BI = mBI[tid][0];
            merge2(B1, B2, BI, mB1[tid][1], mB2[tid][1], mBI[tid][1]);
            int m = m0 + tid;
            AB1[m * NS + s]  = B1;
            AB2[m * NS + s]  = B2;
            AIdx[m * NS + s] = BI;
        }
    }
    grid.sync();

    // ======== phase 4: merge stripes + write clear outputs (fully parallel) ========
    {
        int gw = bx * 4 + wid;            // 0..1023; 2 prompts per wave
        for (int m = gw; m < PROMPT_LEN; m += 1024) {
            int s = lane & 7;
            float b1 = AB1[m * NS + s];
            float b2 = AB2[m * NS + s];
            int   bi = AIdx[m * NS + s];
            #pragma unroll
            for (int msk = 1; msk <= 4; msk <<= 1) {
                float y1 = __shfl_xor(b1, msk, 64);
                float y2 = __shfl_xor(b2, msk, 64);
                int   yi = __shfl_xor(bi, msk, 64);
                merge2(b1, b2, bi, y1, y2, yi);
            }
            if (rawCount > CAND_MAX || b2 - b1 < EPS) {
                if (lane == 0) {
                    int pos = atomicAdd((int*)&scal[3], 1);
                    amb[pos] = m;
                }
            } else {
                const float* crow = clip + (size_t)bi * DIM;
                const float* prow = prompt + (size_t)m * DIM;
                #pragma unroll
                for (int i = 0; i < 3; ++i) {
                    float4 c = ((const float4*)crow)[i * 64 + lane];
                    float4 p = ((const float4*)prow)[i * 64 + lane];
                    float4 o;
                    o.x = (c.x - p.x) + p.x;
                    o.y = (c.y - p.y) + p.y;
                    o.z = (c.z - p.z) + p.z;
                    o.w = (c.w - p.w) + p.w;
                    ((float4*)(out + (size_t)m * DIM))[i * 64 + lane] = o;
                }
                if (lane == 0) out[(size_t)PROMPT_LEN * DIM + m] = (float)bi;
            }
        }
    }
    grid.sync();

    // ======== phase 5: exact fp64 rescan of ambiguous prompts ========
    {
        int nAmb = (int)scal[3];
        for (int a = bx; a < nAmb; a += 256) {
            int m = amb[a];
            const float* prow = prompt + (size_t)m * DIM;
            double pd[12];
            #pragma unroll
            for (int i = 0; i < 3; ++i) {
                float4 v = ((const float4*)prow)[i * 64 + lane];
                pd[i*4+0] = (double)v.x; pd[i*4+1] = (double)v.y;
                pd[i*4+2] = (double)v.z; pd[i*4+3] = (double)v.w;
            }
            double best = 1e300;
            int bestIdx = 0x7fffffff;
            for (int ci = wid; ci < rawCount; ci += 4) {
                int v = cand[ci];
                const float* crow = clip + (size_t)v * DIM;
                double sd = 0.0;
                #pragma unroll
                for (int i = 0; i < 3; ++i) {
                    float4 c = ((const float4*)crow)[i * 64 + lane];
                    double d0 = (double)c.x - pd[i*4+0];
                    double d1 = (double)c.y - pd[i*4+1];
                    double d2 = (double)c.z - pd[i*4+2];
                    double d3 = (double)c.w - pd[i*4+3];
                    sd = fma(d0, d0, sd); sd = fma(d1, d1, sd);
                    sd = fma(d2, d2, sd); sd = fma(d3, d3, sd);
                }
                #pragma unroll
                for (int msk = 32; msk >= 1; msk >>= 1) sd += __shfl_xor(sd, msk, 64);
                if (sd < best || (sd == best && v < bestIdx)) { best = sd; bestIdx = v; }
            }
            if (lane == 0) { fB[wid] = best; fI[wid] = bestIdx; }
            __syncthreads();
            if (tid == 0) {
                double b = fB[0]; int bi2 = fI[0];
                #pragma unroll
                for (int w = 1; w < 4; ++w)
                    if (fB[w] < b || (fB[w] == b && fI[w] < bi2)) { b = fB[w]; bi2 = fI[w]; }
                sWin = bi2;
            }
            __syncthreads();
            int win = sWin;

            if (tid < 192) {
                float4 c = ((const float4*)(clip + (size_t)win * DIM))[tid];
                float4 p = ((const float4*)prow)[tid];
                float4 o;
                o.x = (c.x - p.x) + p.x;
                o.y = (c.y - p.y) + p.y;
                o.z = (c.z - p.z) + p.z;
                o.w = (c.w - p.w) + p.w;
                ((float4*)(out + (size_t)m * DIM))[tid] = o;
            }
            if (tid == 0) out[(size_t)PROMPT_LEN * DIM + m] = (float)win;
            __syncthreads();
        }
    }
}

extern "C" void kernel_launch(void* const* d_in, const int* in_sizes, int n_in,
                              void* d_out, int out_size, void* d_ws, size_t ws_size,
                              hipStream_t stream) {
    const float* prompt = (const float*)d_in[0];
    const float* clip   = (const float*)d_in[1];
    float* out = (float*)d_out;

    char* w = (char*)d_ws;
    float*    csq     = (float*)w;                 w += (size_t)VOCAB * 4;
    int*      cand    = (int*)w;                   w += (size_t)VOCAB * 4;
    float*    candCsq = (float*)w;                 w += (size_t)VOCAB * 4;
    unsigned* scal    = (unsigned*)w;              w += 32;
    float*    AB1     = (float*)w;                 w += (size_t)PROMPT_LEN * NS * 4;
    float*    AB2     = (float*)w;                 w += (size_t)PROMPT_LEN * NS * 4;
    int*      AIdx    = (int*)w;                   w += (size_t)PROMPT_LEN * NS * 4;
    int*      amb     = (int*)w;                   w += (size_t)PROMPT_LEN * 4;
    unsigned short* PbH = (unsigned short*)w;      w += (size_t)PROMPT_LEN * DIM * 2;
    unsigned short* PbL = (unsigned short*)w;      w += (size_t)PROMPT_LEN * DIM * 2;
    unsigned short* CbH = (unsigned short*)w;      w += (size_t)CAND_MAX * DIM * 2;
    unsigned short* CbL = (unsigned short*)w;      w += (size_t)CAND_MAX * DIM * 2;

    void* args[] = {
        (void*)&prompt, (void*)&clip, (void*)&csq, (void*)&cand, (void*)&candCsq,
        (void*)&scal, (void*)&AB1, (void*)&AB2, (void*)&AIdx, (void*)&amb,
        (void*)&PbH, (void*)&PbL, (void*)&CbH, (void*)&CbL, (void*)&out
    };
    hipLaunchCooperativeKernel((const void*)k_all, dim3(256), dim3(256),
                               args, 0, stream);
}

// Round 4
// 306.177 us; speedup vs baseline: 1.6465x; 1.6465x over previous
//
#include <hip/hip_runtime.h>
#include <float.h>

#define PROMPT_LEN 2048
#define VOCAB 49408
#define DIM 768
#define ROWS_TOTAL (VOCAB + PROMPT_LEN)   // 51456
#define NS 32          // candidate stripes (R1-verified)
#define BM 64          // prompts per tile
#define BN 64          // candidates per tile
#define KCH 128        // k-chunk (bf16 elems)
#define NCHUNK (DIM / KCH)   // 6
#define LDK (KCH + 8)  // LDS pitch in ushorts: 272B -> 2-way bank alias (free)
#define CAND_MAX 4096
#define EPS 0.008f     // fp32 ambiguity margin (validated earlier rounds)

typedef __attribute__((ext_vector_type(8))) short s8v;   // 8 bf16 = 4 VGPR (MFMA A/B frag)
typedef __attribute__((ext_vector_type(4))) float fx4;   // MFMA C/D frag

// ws: csq | cand | candCsq | scal | AB1 | AB2 | AIdx | amb | PbH | PbL | CbH | CbL
// scal: [0]=cand count, [1]=cmin bits, [2]=pmax bits, [3]=amb count
// ws poison 0xAAAAAAAA: atomicMin-on-uint / atomicMax-on-int are poison-safe;
// scal[0] zeroed in k_sumsq block 0 (read next kernel); scal[3] zeroed in
// k_compact_convert block 0 (read in k_fallback, 2 kernels later).

__device__ inline unsigned short f2bf(float x) {         // RN-even f32->bf16
    unsigned u = __float_as_uint(x);
    u += 0x7FFFu + ((u >> 16) & 1u);
    return (unsigned short)(u >> 16);
}

__device__ inline void conv_row(const float* __restrict__ src,
                                unsigned short* __restrict__ dH,
                                unsigned short* __restrict__ dL, int lane) {
    #pragma unroll
    for (int i = 0; i < 3; ++i) {
        float4 x = ((const float4*)src)[i * 64 + lane];
        ushort4 h, l;
        h.x = f2bf(x.x); l.x = f2bf(x.x - __uint_as_float((unsigned)h.x << 16));
        h.y = f2bf(x.y); l.y = f2bf(x.y - __uint_as_float((unsigned)h.y << 16));
        h.z = f2bf(x.z); l.z = f2bf(x.z - __uint_as_float((unsigned)h.z << 16));
        h.w = f2bf(x.w); l.w = f2bf(x.w - __uint_as_float((unsigned)h.w << 16));
        ((ushort4*)dH)[i * 64 + lane] = h;
        ((ushort4*)dL)[i * 64 + lane] = l;
    }
}

__device__ inline void merge2(float& b1, float& b2, int& bi,
                              float y1, float y2, int yi) {
    if (y1 < b1) { b2 = fminf(b1, y2); b1 = y1; bi = yi; }
    else         { b2 = fminf(b2, fminf(y1, y2)); }
}

// ---------------- k_sumsq: 512 blocks x 1024 thr, grid-stride row-pairs ----------------
// 8192 waves over 25728 row-pairs (~3.14 pairs/wave); exactly 2 blocks/CU, no tail.
// Pairs never straddle the clip/prompt boundary (VOCAB even, r even).
__global__ void __launch_bounds__(1024) k_sumsq(const float* __restrict__ prompt,
                                                const float* __restrict__ clip,
                                                float* __restrict__ csq,
                                                unsigned* __restrict__ scal) {
    int tid  = threadIdx.x;
    int wid  = tid >> 6;        // 0..15
    int lane = tid & 63;
    int gw   = blockIdx.x * 16 + wid;       // 0..8191

    if (blockIdx.x == 0 && tid == 0) scal[0] = 0u;

    float locMin = FLT_MAX, locMax = 0.f;
    for (int p = gw; p < ROWS_TOTAL / 2; p += 8192) {
        int r = 2 * p;
        const float* s0 = (r < VOCAB) ? clip + (size_t)r * DIM
                                      : prompt + (size_t)(r - VOCAB) * DIM;
        const float* s1 = (r + 1 < VOCAB) ? clip + (size_t)(r + 1) * DIM
                                          : prompt + (size_t)(r + 1 - VOCAB) * DIM;
        float4 a0 = ((const float4*)s0)[lane];
        float4 a1 = ((const float4*)s0)[64 + lane];
        float4 a2 = ((const float4*)s0)[128 + lane];
        float4 b0 = ((const float4*)s1)[lane];
        float4 b1 = ((const float4*)s1)[64 + lane];
        float4 b2 = ((const float4*)s1)[128 + lane];
        float sA = a0.x*a0.x + a0.y*a0.y + a0.z*a0.z + a0.w*a0.w
                 + a1.x*a1.x + a1.y*a1.y + a1.z*a1.z + a1.w*a1.w
                 + a2.x*a2.x + a2.y*a2.y + a2.z*a2.z + a2.w*a2.w;
        float sB = b0.x*b0.x + b0.y*b0.y + b0.z*b0.z + b0.w*b0.w
                 + b1.x*b1.x + b1.y*b1.y + b1.z*b1.z + b1.w*b1.w
                 + b2.x*b2.x + b2.y*b2.y + b2.z*b2.z + b2.w*b2.w;
        #pragma unroll
        for (int m = 32; m >= 1; m >>= 1) {
            sA += __shfl_xor(sA, m, 64);
            sB += __shfl_xor(sB, m, 64);
        }
        if (r < VOCAB)     locMin = fminf(locMin, sA); else locMax = fmaxf(locMax, sA);
        if (r + 1 < VOCAB) locMin = fminf(locMin, sB); else locMax = fmaxf(locMax, sB);
        if (lane == 0) {
            if (r < VOCAB)     csq[r] = sA;
            if (r + 1 < VOCAB) csq[r + 1] = sB;
        }
    }
    __shared__ float smn[16], smx[16];
    if (lane == 0) { smn[wid] = locMin; smx[wid] = locMax; }
    __syncthreads();
    if (tid == 0) {
        float mn = FLT_MAX, mx = 0.f;
        #pragma unroll
        for (int w = 0; w < 16; ++w) { mn = fminf(mn, smn[w]); mx = fmaxf(mx, smx[w]); }
        atomicMin(&scal[1], __float_as_uint(mn));            // uint: poison-safe
        atomicMax((int*)&scal[2], (int)__float_as_uint(mx)); // int: poison-safe
    }
}

// ---------------- k_compact_convert: prune + split-bf16 conversion (balanced) --------
// Grid 512 x 256. Blocks 0..192 compact their 256-vocab slice and convert their
// own kept rows. ALL 512 blocks convert prompt rows (2048 waves -> 1 row/wave).
__global__ void __launch_bounds__(256) k_compact_convert(
        const float* __restrict__ prompt, const float* __restrict__ clip,
        const float* __restrict__ csq,
        int* __restrict__ cand, float* __restrict__ candCsq,
        unsigned* __restrict__ scal,
        unsigned short* __restrict__ PbH, unsigned short* __restrict__ PbL,
        unsigned short* __restrict__ CbH, unsigned short* __restrict__ CbL) {
    int tid  = threadIdx.x;
    int wid  = tid >> 6;
    int lane = tid & 63;
    int bx   = blockIdx.x;

    if (bx == 0 && tid == 0) scal[3] = 0u;    // amb count (used 2 kernels later)

    // --- prompt conversion: exactly one row per wave ---
    {
        int r = bx * 4 + wid;                 // 0..2047
        conv_row(prompt + (size_t)r * DIM,
                 PbH + (size_t)r * DIM, PbL + (size_t)r * DIM, lane);
    }

    if (bx >= VOCAB / 256) return;            // blocks 193..511: prompt-only

    // --- compact my 256-vocab slice ---
    float cmin    = __uint_as_float(scal[1]);
    float pmax_sq = __uint_as_float(scal[2]);
    float B  = sqrtf(pmax_sq) * 1.0001f + 1e-6f;
    float U  = cmin + 2.f * B * sqrtf(cmin) + 1.0f;
    float sT = B + sqrtf(B * B + U);
    float T  = sT * sT;

    int v = bx * 256 + tid;
    __shared__ int cntS, basep;
    __shared__ int kvS[256];
    if (tid == 0) cntS = 0;
    __syncthreads();
    float cs = csq[v];
    int keep = (cs <= T);
    int pos = 0;
    if (keep) pos = atomicAdd(&cntS, 1);
    __syncthreads();
    if (tid == 0 && cntS > 0) basep = atomicAdd((int*)&scal[0], cntS);
    __syncthreads();
    if (keep) {
        int dst = basep + pos;
        cand[dst]    = v;
        candCsq[dst] = cs;
        kvS[pos] = v;
    }
    __syncthreads();

    // --- convert my kept rows (wave-parallel) ---
    int nk = cntS;
    for (int i = wid; i < nk; i += 4) {
        int dst = basep + i;
        if (dst >= CAND_MAX) break;           // overflow -> all-amb fallback path
        conv_row(clip + (size_t)kvS[i] * DIM,
                 CbH + (size_t)dst * DIM, CbL + (size_t)dst * DIM, lane);
    }
}

// ---------------- k_score: split-bf16 MFMA scorer (R1-verified body) ----------------
// cross = Ahi*Bhi + Alo*Bhi + Ahi*Blo  (|err on 2*cross| << EPS/2; lo*lo dropped).
// Block = (m-tile, stripe): 64x64 tile, 4 waves as 2x2 quadrants, each wave
// 2x2 fragments of mfma_f32_16x16x32_bf16. K-chunks of 128 with 1-deep
// register prefetch. Grid 32*NS = 1024 blocks.
__global__ void __launch_bounds__(256, 2)
k_score(const unsigned short* __restrict__ PbH, const unsigned short* __restrict__ PbL,
        const unsigned short* __restrict__ CbH, const unsigned short* __restrict__ CbL,
        const float* __restrict__ candCsq, const int* __restrict__ cand,
        const unsigned* __restrict__ scal,
        float* __restrict__ AB1, float* __restrict__ AB2, int* __restrict__ AIdx) {
    int mi = blockIdx.x & 31;
    int s  = blockIdx.x >> 5;        // 0..31
    int m0 = mi * BM;
    int count = (int)scal[0];
    if (count > CAND_MAX) count = CAND_MAX;   // overflow handled by k_merge->fallback
    int ntiles = (count + BN - 1) / BN;

    int tid  = threadIdx.x;
    int lane = tid & 63;
    int wid  = tid >> 6;
    int wr32 = (wid >> 1) * 32;      // wave row quadrant base
    int wc32 = (wid & 1) * 32;       // wave col quadrant base
    int l15  = lane & 15;
    int l4   = lane >> 4;

    __shared__ unsigned short Ah[BM][LDK], Al[BM][LDK];
    __shared__ unsigned short Bh[BN][LDK], Bl[BN][LDK];
    __shared__ int   candS[BN];
    __shared__ float csqS[BN];
    __shared__ float mB1[BM][2], mB2[BM][2];
    __shared__ int   mBI[BM][2];

    // staging map: j = tid + 256*f -> row j>>4, ushort8-col j&15  (16 u8/row)
    int srow[4], scol[4], offA[4];
    #pragma unroll
    for (int f = 0; f < 4; ++f) {
        int j = tid + 256 * f;
        srow[f] = j >> 4;
        scol[f] = (j & 15) * 8;
        offA[f] = (m0 + srow[f]) * DIM + scol[f];
    }

    // running per-lane top-2 triples: [fm][j] -> row wr32+fm*16+l4*4+j
    float rb1[2][4], rb2[2][4]; int rbi[2][4];
    #pragma unroll
    for (int fm = 0; fm < 2; ++fm)
        #pragma unroll
        for (int j = 0; j < 4; ++j) { rb1[fm][j] = FLT_MAX; rb2[fm][j] = FLT_MAX; rbi[fm][j] = 0x7fffffff; }

    for (int tile = s; tile < ntiles; tile += NS) {
        __syncthreads();                       // prev tile's csqS/candS reads done
        if (tid < BN) {
            int ci = tile * BN + tid;
            candS[tid] = (ci < count) ? cand[ci] : 0;
            csqS[tid]  = (ci < count) ? candCsq[ci] : FLT_MAX;
        }

        int offB[4];
        #pragma unroll
        for (int f = 0; f < 4; ++f) {
            int rowc = tile * BN + srow[f];
            if (rowc >= count) rowc = 0;       // masked via csqS
            offB[f] = rowc * DIM + scol[f];
        }

        fx4 acc00 = {0.f,0.f,0.f,0.f}, acc01 = {0.f,0.f,0.f,0.f};
        fx4 acc10 = {0.f,0.f,0.f,0.f}, acc11 = {0.f,0.f,0.f,0.f};

        s8v rAh[4], rAl[4], rBh[4], rBl[4];
        #pragma unroll
        for (int f = 0; f < 4; ++f) {          // chunk 0 loads
            rAh[f] = *(const s8v*)(PbH + offA[f]);
            rAl[f] = *(const s8v*)(PbL + offA[f]);
            rBh[f] = *(const s8v*)(CbH + offB[f]);
            rBl[f] = *(const s8v*)(CbL + offB[f]);
        }

        #pragma unroll
        for (int kc = 0; kc < NCHUNK; ++kc) {
            __syncthreads();                   // LDS free to overwrite
            #pragma unroll
            for (int f = 0; f < 4; ++f) {
                *(s8v*)&Ah[srow[f]][scol[f]] = rAh[f];
                *(s8v*)&Al[srow[f]][scol[f]] = rAl[f];
                *(s8v*)&Bh[srow[f]][scol[f]] = rBh[f];
                *(s8v*)&Bl[srow[f]][scol[f]] = rBl[f];
            }
            __syncthreads();                   // writes visible
            if (kc + 1 < NCHUNK) {             // prefetch next chunk under MFMA
                int off = (kc + 1) * KCH;
                #pragma unroll
                for (int f = 0; f < 4; ++f) {
                    rAh[f] = *(const s8v*)(PbH + offA[f] + off);
                    rAl[f] = *(const s8v*)(PbL + offA[f] + off);
                    rBh[f] = *(const s8v*)(CbH + offB[f] + off);
                    rBl[f] = *(const s8v*)(CbL + offB[f] + off);
                }
            }
            #pragma unroll
            for (int kk = 0; kk < KCH / 32; ++kk) {
                int ko = kk * 32 + l4 * 8;     // lane k-slice (8 contiguous bf16)
                s8v ah0 = *(const s8v*)&Ah[wr32      + l15][ko];
                s8v ah1 = *(const s8v*)&Ah[wr32 + 16 + l15][ko];
                s8v al0 = *(const s8v*)&Al[wr32      + l15][ko];
                s8v al1 = *(const s8v*)&Al[wr32 + 16 + l15][ko];
                s8v bh0 = *(const s8v*)&Bh[wc32      + l15][ko];
                s8v bh1 = *(const s8v*)&Bh[wc32 + 16 + l15][ko];
                s8v bl0 = *(const s8v*)&Bl[wc32      + l15][ko];
                s8v bl1 = *(const s8v*)&Bl[wc32 + 16 + l15][ko];
                acc00 = __builtin_amdgcn_mfma_f32_16x16x32_bf16(ah0, bh0, acc00, 0, 0, 0);
                acc01 = __builtin_amdgcn_mfma_f32_16x16x32_bf16(ah0, bh1, acc01, 0, 0, 0);
                acc10 = __builtin_amdgcn_mfma_f32_16x16x32_bf16(ah1, bh0, acc10, 0, 0, 0);
                acc11 = __builtin_amdgcn_mfma_f32_16x16x32_bf16(ah1, bh1, acc11, 0, 0, 0);
                acc00 = __builtin_amdgcn_mfma_f32_16x16x32_bf16(al0, bh0, acc00, 0, 0, 0);
                acc01 = __builtin_amdgcn_mfma_f32_16x16x32_bf16(al0, bh1, acc01, 0, 0, 0);
                acc10 = __builtin_amdgcn_mfma_f32_16x16x32_bf16(al1, bh0, acc10, 0, 0, 0);
                acc11 = __builtin_amdgcn_mfma_f32_16x16x32_bf16(al1, bh1, acc11, 0, 0, 0);
                acc00 = __builtin_amdgcn_mfma_f32_16x16x32_bf16(ah0, bl0, acc00, 0, 0, 0);
                acc01 = __builtin_amdgcn_mfma_f32_16x16x32_bf16(ah0, bl1, acc01, 0, 0, 0);
                acc10 = __builtin_amdgcn_mfma_f32_16x16x32_bf16(ah1, bl0, acc10, 0, 0, 0);
                acc11 = __builtin_amdgcn_mfma_f32_16x16x32_bf16(ah1, bl1, acc11, 0, 0, 0);
            }
        }

        // fold tile d2. D layout (m89): col = lane&15, row = (lane>>4)*4 + reg.
        float cs0 = csqS[wc32 + l15];       int v0 = candS[wc32 + l15];
        float cs1 = csqS[wc32 + 16 + l15];  int v1 = candS[wc32 + 16 + l15];
        #pragma unroll
        for (int j = 0; j < 4; ++j) {
            if (cs0 < FLT_MAX) {
                float d2 = fmaf(-2.f, acc00[j], cs0);
                if (d2 < rb1[0][j]) { rb2[0][j] = rb1[0][j]; rb1[0][j] = d2; rbi[0][j] = v0; }
                else if (d2 <= rb2[0][j]) rb2[0][j] = d2;
                d2 = fmaf(-2.f, acc10[j], cs0);
                if (d2 < rb1[1][j]) { rb2[1][j] = rb1[1][j]; rb1[1][j] = d2; rbi[1][j] = v0; }
                else if (d2 <= rb2[1][j]) rb2[1][j] = d2;
            }
            if (cs1 < FLT_MAX) {
                float d2 = fmaf(-2.f, acc01[j], cs1);
                if (d2 < rb1[0][j]) { rb2[0][j] = rb1[0][j]; rb1[0][j] = d2; rbi[0][j] = v1; }
                else if (d2 <= rb2[0][j]) rb2[0][j] = d2;
                d2 = fmaf(-2.f, acc11[j], cs1);
                if (d2 < rb1[1][j]) { rb2[1][j] = rb1[1][j]; rb1[1][j] = d2; rbi[1][j] = v1; }
                else if (d2 <= rb2[1][j]) rb2[1][j] = d2;
            }
        }
    }

    // reduce 16 lanes (same l4 group = same rows), then across the 2 wc halves via LDS
    #pragma unroll
    for (int fm = 0; fm < 2; ++fm)
        #pragma unroll
        for (int j = 0; j < 4; ++j) {
            float b1 = rb1[fm][j], b2 = rb2[fm][j]; int bi = rbi[fm][j];
            #pragma unroll
            for (int msk = 1; msk <= 8; msk <<= 1) {
                float y1 = __shfl_xor(b1, msk, 64);
                float y2 = __shfl_xor(b2, msk, 64);
                int   yi = __shfl_xor(bi, msk, 64);
                merge2(b1, b2, bi, y1, y2, yi);
            }
            if (l15 == 0) {
                int rl = wr32 + fm * 16 + l4 * 4 + j;
                mB1[rl][wid & 1] = b1; mB2[rl][wid & 1] = b2; mBI[rl][wid & 1] = bi;
            }
        }
    __syncthreads();
    if (tid < BM) {
        float B1 = mB1[tid][0], B2 = mB2[tid][0]; int BI = mBI[tid][0];
        merge2(B1, B2, BI, mB1[tid][1], mB2[tid][1], mBI[tid][1]);
        int m = m0 + tid;
        AB1[m * NS + s]  = B1;
        AB2[m * NS + s]  = B2;
        AIdx[m * NS + s] = BI;
    }
}

// ---------------- k_merge: wave per prompt, 32 stripes (R1-verified) ----------------
__global__ void __launch_bounds__(256) k_merge(const float* __restrict__ prompt,
                                               const float* __restrict__ clip,
                                               const float* __restrict__ AB1,
                                               const float* __restrict__ AB2,
                                               const int* __restrict__ AIdx,
                                               unsigned* __restrict__ scal,
                                               int* __restrict__ amb,
                                               float* __restrict__ out) {
    int wid  = threadIdx.x >> 6;
    int lane = threadIdx.x & 63;
    int m = blockIdx.x * 4 + wid;
    int s = lane & 31;
    int count = (int)scal[0];

    float b1 = AB1[m * NS + s];
    float b2 = AB2[m * NS + s];
    int   bi = AIdx[m * NS + s];
    #pragma unroll
    for (int msk = 1; msk <= 16; msk <<= 1) {
        float y1 = __shfl_xor(b1, msk, 64);
        float y2 = __shfl_xor(b2, msk, 64);
        int   yi = __shfl_xor(bi, msk, 64);
        merge2(b1, b2, bi, y1, y2, yi);
    }

    if (count > CAND_MAX || b2 - b1 < EPS) {   // overflow => exact fallback for all
        if (lane == 0) {
            int pos = atomicAdd((int*)&scal[3], 1);
            amb[pos] = m;
        }
    } else {
        const float* crow = clip + (size_t)bi * DIM;
        const float* prow = prompt + (size_t)m * DIM;
        #pragma unroll
        for (int i = 0; i < 3; ++i) {
            float4 c = ((const float4*)crow)[i * 64 + lane];
            float4 p = ((const float4*)prow)[i * 64 + lane];
            float4 o;
            o.x = (c.x - p.x) + p.x;
            o.y = (c.y - p.y) + p.y;
            o.z = (c.z - p.z) + p.z;
            o.w = (c.w - p.w) + p.w;
            ((float4*)(out + (size_t)m * DIM))[i * 64 + lane] = o;
        }
        if (lane == 0) out[(size_t)PROMPT_LEN * DIM + m] = (float)bi;
    }
}

// ---------------- k_fallback (R1-verified): exact fp64 rescan ----------------
__global__ void __launch_bounds__(1024) k_fallback(const float* __restrict__ prompt,
                                                   const float* __restrict__ clip,
                                                   const int* __restrict__ cand,
                                                   const unsigned* __restrict__ scal,
                                                   const int* __restrict__ amb,
                                                   float* __restrict__ out) {
    int nAmb  = (int)scal[3];
    int count = (int)scal[0];
    int tid  = threadIdx.x;
    int wid  = tid >> 6;
    int lane = tid & 63;

    __shared__ double fB[16];
    __shared__ int    fI[16];
    __shared__ int    sWin;

    for (int a = blockIdx.x; a < nAmb; a += gridDim.x) {
        int m = amb[a];
        const float* prow = prompt + (size_t)m * DIM;
        double pd[12];
        #pragma unroll
        for (int i = 0; i < 3; ++i) {
            float4 v = ((const float4*)prow)[i * 64 + lane];
            pd[i*4+0] = (double)v.x; pd[i*4+1] = (double)v.y;
            pd[i*4+2] = (double)v.z; pd[i*4+3] = (double)v.w;
        }
        double best = 1e300;
        int bestIdx = 0x7fffffff;
        for (int ci = wid; ci < count; ci += 16) {
            int v = cand[ci];
            const float* crow = clip + (size_t)v * DIM;
            double sd = 0.0;
            #pragma unroll
            for (int i = 0; i < 3; ++i) {
                float4 c = ((const float4*)crow)[i * 64 + lane];
                double d0 = (double)c.x - pd[i*4+0];
                double d1 = (double)c.y - pd[i*4+1];
                double d2 = (double)c.z - pd[i*4+2];
                double d3 = (double)c.w - pd[i*4+3];
                sd = fma(d0, d0, sd); sd = fma(d1, d1, sd);
                sd = fma(d2, d2, sd); sd = fma(d3, d3, sd);
            }
            #pragma unroll
            for (int msk = 32; msk >= 1; msk >>= 1) sd += __shfl_xor(sd, msk, 64);
            if (sd < best || (sd == best && v < bestIdx)) { best = sd; bestIdx = v; }
        }
        if (lane == 0) { fB[wid] = best; fI[wid] = bestIdx; }
        __syncthreads();
        if (tid == 0) {
            double b = fB[0]; int bi2 = fI[0];
            #pragma unroll
            for (int w = 1; w < 16; ++w)
                if (fB[w] < b || (fB[w] == b && fI[w] < bi2)) { b = fB[w]; bi2 = fI[w]; }
            sWin = bi2;
        }
        __syncthreads();
        int win = sWin;

        if (tid < 192) {
            float4 c = ((const float4*)(clip + (size_t)win * DIM))[tid];
            float4 p = ((const float4*)prow)[tid];
            float4 o;
            o.x = (c.x - p.x) + p.x;
            o.y = (c.y - p.y) + p.y;
            o.z = (c.z - p.z) + p.z;
            o.w = (c.w - p.w) + p.w;
            ((float4*)(out + (size_t)m * DIM))[tid] = o;
        }
        if (tid == 0) out[(size_t)PROMPT_LEN * DIM + m] = (float)win;
        __syncthreads();
    }
}

extern "C" void kernel_launch(void* const* d_in, const int* in_sizes, int n_in,
                              void* d_out, int out_size, void* d_ws, size_t ws_size,
                              hipStream_t stream) {
    const float* prompt = (const float*)d_in[0];
    const float* clip   = (const float*)d_in[1];
    float* out = (float*)d_out;

    char* w = (char*)d_ws;
    float*    csq     = (float*)w;                 w += (size_t)VOCAB * 4;
    int*      cand    = (int*)w;                   w += (size_t)VOCAB * 4;
    float*    candCsq = (float*)w;                 w += (size_t)VOCAB * 4;
    unsigned* scal    = (unsigned*)w;              w += 32;
    float*    AB1     = (float*)w;                 w += (size_t)PROMPT_LEN * NS * 4;
    float*    AB2     = (float*)w;                 w += (size_t)PROMPT_LEN * NS * 4;
    int*      AIdx    = (int*)w;                   w += (size_t)PROMPT_LEN * NS * 4;
    int*      amb     = (int*)w;                   w += (size_t)PROMPT_LEN * 4;
    unsigned short* PbH = (unsigned short*)w;      w += (size_t)PROMPT_LEN * DIM * 2;
    unsigned short* PbL = (unsigned short*)w;      w += (size_t)PROMPT_LEN * DIM * 2;
    unsigned short* CbH = (unsigned short*)w;      w += (size_t)CAND_MAX * DIM * 2;
    unsigned short* CbL = (unsigned short*)w;      w += (size_t)CAND_MAX * DIM * 2;

    k_sumsq<<<512, 1024, 0, stream>>>(prompt, clip, csq, scal);
    k_compact_convert<<<512, 256, 0, stream>>>(prompt, clip, csq, cand, candCsq,
                                               scal, PbH, PbL, CbH, CbL);
    k_score<<<32 * NS, 256, 0, stream>>>(PbH, PbL, CbH, CbL, candCsq, cand, scal,
                                         AB1, AB2, AIdx);
    k_merge<<<PROMPT_LEN / 4, 256, 0, stream>>>(prompt, clip, AB1, AB2, AIdx, scal, amb, out);
    k_fallback<<<128, 1024, 0, stream>>>(prompt, clip, cand, scal, amb, out);
}